// Round 6
// baseline (3643.074 us; speedup 1.0000x reference)
//
#include <hip/hip_runtime.h>
#include <math.h>

#define T_ENC 2048
#define BATCH 32
#define DM    256
#define HID   512
#define VOC   32
#define LEN   100
#define NBLK  128
#define NTHR  512

// ws layout (floats):
// [0,      49152)    gi_const [b][1536]
// [49152,  98304)    gi_emb   [v][1536]
// [98304, 1753088)   h bufs: 101 x [b][k] (32x512), fresh buffer per step
//    precompute-only aliases (dead before k_seq overwrites; safe because the
//    k_seq dispatch's acquire invalidates all XCD L2s):
//    score    at 131072 (= h bufs 2..5), ctx_part at 196608 (= bufs 6..7),
//    ctx      at 229376 (= buf 8 half)
// [1753088,1754112)  flags: 128 ints padded x8 (32B apart)

// ---------- precompute ----------

__global__ void k_score(const float* __restrict__ enc, const float* __restrict__ Wattn,
                        float* __restrict__ score) {
  int wid  = (blockIdx.x * blockDim.x + threadIdx.x) >> 6;
  int lane = threadIdx.x & 63;
  int b = wid & 31, t = wid >> 5;
  const float4 e4 = *(const float4*)(enc + (size_t)(t * BATCH + b) * DM + lane * 4);
  const float4 w4 = *(const float4*)(Wattn + HID + lane * 4);
  float v = e4.x * w4.x + e4.y * w4.y + e4.z * w4.z + e4.w * w4.w;
  for (int o = 32; o; o >>= 1) v += __shfl_down(v, o);
  if (lane == 0) score[b * T_ENC + t] = v;
}

__global__ void k_softmax(float* __restrict__ score) {
  int b = blockIdx.x, tid = threadIdx.x;
  float* row = score + b * T_ENC;
  float4 v0 = *(const float4*)(row + tid * 8);
  float4 v1 = *(const float4*)(row + tid * 8 + 4);
  float m = fmaxf(fmaxf(fmaxf(v0.x, v0.y), fmaxf(v0.z, v0.w)),
                  fmaxf(fmaxf(v1.x, v1.y), fmaxf(v1.z, v1.w)));
  for (int o = 32; o; o >>= 1) m = fmaxf(m, __shfl_xor(m, o));
  __shared__ float redm[8];
  __shared__ float reds[8];
  if ((tid & 63) == 0) redm[tid >> 6] = m;
  __syncthreads();
  m = fmaxf(fmaxf(redm[0], redm[1]), fmaxf(redm[2], redm[3]));
  float e0 = expf(v0.x - m), e1 = expf(v0.y - m), e2 = expf(v0.z - m), e3 = expf(v0.w - m);
  float e4 = expf(v1.x - m), e5 = expf(v1.y - m), e6 = expf(v1.z - m), e7 = expf(v1.w - m);
  float s = ((e0 + e1) + (e2 + e3)) + ((e4 + e5) + (e6 + e7));
  for (int o = 32; o; o >>= 1) s += __shfl_xor(s, o);
  if ((tid & 63) == 0) reds[tid >> 6] = s;
  __syncthreads();
  s = (reds[0] + reds[1]) + (reds[2] + reds[3]);
  float inv = 1.f / s;
  float4 o0 = {e0 * inv, e1 * inv, e2 * inv, e3 * inv};
  float4 o1 = {e4 * inv, e5 * inv, e6 * inv, e7 * inv};
  *(float4*)(row + tid * 8)     = o0;
  *(float4*)(row + tid * 8 + 4) = o1;
}

__global__ void k_ctxpart(const float* __restrict__ enc, const float* __restrict__ aw,
                          float* __restrict__ ctx_part) {
  int b = blockIdx.x >> 2, tg = blockIdx.x & 3;
  int w = threadIdx.x >> 6, lane = threadIdx.x & 63;
  float4 acc = {0.f, 0.f, 0.f, 0.f};
  for (int i = 0; i < 128; ++i) {
    int t = tg * 512 + w * 128 + i;
    float a = aw[b * T_ENC + t];
    const float4 e4 = *(const float4*)(enc + (size_t)(t * BATCH + b) * DM + lane * 4);
    acc.x += a * e4.x; acc.y += a * e4.y; acc.z += a * e4.z; acc.w += a * e4.w;
  }
  __shared__ float4 part[4][64];
  part[w][lane] = acc;
  __syncthreads();
  if (w == 0) {
    float4 s = part[0][lane], p1 = part[1][lane], p2 = part[2][lane], p3 = part[3][lane];
    s.x += p1.x + p2.x + p3.x; s.y += p1.y + p2.y + p3.y;
    s.z += p1.z + p2.z + p3.z; s.w += p1.w + p2.w + p3.w;
    *(float4*)(ctx_part + (size_t)(tg * BATCH + b) * DM + lane * 4) = s;
  }
}

__global__ void k_ctxreduce(const float* __restrict__ ctx_part, float* __restrict__ ctx) {
  int b = blockIdx.x, d = threadIdx.x;
  float s = 0.f;
  for (int tg = 0; tg < 4; ++tg) s += ctx_part[(size_t)(tg * BATCH + b) * DM + d];
  ctx[b * DM + d] = s;
}

__global__ void k_gitab(const float* __restrict__ Wih, const float* __restrict__ bih,
                        const float* __restrict__ emb, const float* __restrict__ ctx,
                        float* __restrict__ gi_const, float* __restrict__ gi_emb) {
  int idx = threadIdx.x & 31, rs = threadIdx.x >> 5;
  int row = blockIdx.x * 8 + rs;
  const float* wr = Wih + (size_t)row * (2 * DM);
  const float* c = ctx + idx * DM;
  const float* e = emb + idx * DM;
  float accC = 0.f, accE = 0.f;
  for (int k = 0; k < DM; k += 4) {
    float4 we = *(const float4*)(wr + k);
    float4 wc = *(const float4*)(wr + DM + k);
    float4 cv = *(const float4*)(c + k);
    float4 ev = *(const float4*)(e + k);
    accE += we.x * ev.x + we.y * ev.y + we.z * ev.z + we.w * ev.w;
    accC += wc.x * cv.x + wc.y * cv.y + wc.z * cv.z + wc.w * cv.w;
  }
  gi_const[idx * 1536 + row] = accC + bih[row];
  gi_emb[idx * 1536 + row]   = accE;
}

__global__ void k_init(float* __restrict__ h0, int* __restrict__ flags) {
  int i = blockIdx.x * blockDim.x + threadIdx.x;
  if (i < HID * BATCH) h0[i] = 0.f;
  if (i < 1024) flags[i] = 0;
}

// ---------- persistent recurrence ----------
// 128 blocks x 512 thr = 4 batch-groups(8 b) x 32 dim-groups(16 d).
// All cross-block data flows ONLY through h bufs (fresh address per step).
// Per block per step: local pred(8bx32v)+argmax (redundant), gh partials,
// gates, h write, flag-vector barrier (parallel stores, no RMW serialization).
__global__ __launch_bounds__(NTHR) void k_seq(
    const float* __restrict__ Whh, const float* __restrict__ bhh,
    const float* __restrict__ Wout, const float* __restrict__ bout,
    const float* __restrict__ gic, const float* __restrict__ gie,
    float* __restrict__ hbufs, int* __restrict__ flags,
    float* __restrict__ out) {
  const int tid = threadIdx.x, bk = blockIdx.x;
  const int B0 = (bk >> 5) * 8;      // batch-group base
  const int D0 = (bk & 31) * 16;     // dim-group base
  const bool isOutBlk = ((bk & 31) == 0);

  __shared__ float ghp[4][3][16][8];   // [ks][gate][d][b8]
  __shared__ float predp[2][8][33];    // [kh][b8][v] (pad 33: bank-safe)
  __shared__ float predLds[8][33];
  __shared__ int   tokLds[8];

  // phase-1 thread maps
  const int b8 = tid & 7;
  const int q  = tid >> 3;             // 0..63
  const int d_gh = q & 15, ks = q >> 4;   // gh: dim, k-quarter
  const int v_pr = q & 31, kh = q >> 5;   // pred: vocab, k-half

  const float* wr0 = Whh + (size_t)(          D0 + d_gh) * HID + ks * 128;
  const float* wr1 = Whh + (size_t)(HID     + D0 + d_gh) * HID + ks * 128;
  const float* wr2 = Whh + (size_t)(2 * HID + D0 + d_gh) * HID + ks * 128;
  const float* wo  = Wout + (size_t)v_pr * HID + kh * 256;
  const float  bov = bout[tid & 31];

  // gates-phase constants (tid < 128): d = tid&15, b = tid>>4
  const int g_d = tid & 15, g_b = tid >> 4;
  float bh0 = 0.f, bh1 = 0.f, bh2 = 0.f;
  if (tid < 128) {
    bh0 = bhh[D0 + g_d]; bh1 = bhh[HID + D0 + g_d]; bh2 = bhh[2 * HID + D0 + g_d];
  }

  for (int s = 0; s <= LEN; ++s) {
    const float* hc = hbufs + (size_t)s * (HID * BATCH);

    // ---- partials: pred (of step s-1) and gh (of step s), both from h_s ----
    if (s > 0) {
      const float* hp = hc + (size_t)(B0 + b8) * HID + kh * 256;
      float a0 = 0.f, a1 = 0.f, a2 = 0.f, a3 = 0.f;
#pragma unroll 8
      for (int k = 0; k < 256; k += 4) {
        float4 h4 = *(const float4*)(hp + k);
        float4 w4 = *(const float4*)(wo + k);
        a0 += h4.x * w4.x; a1 += h4.y * w4.y; a2 += h4.z * w4.z; a3 += h4.w * w4.w;
      }
      predp[kh][b8][v_pr] = (a0 + a1) + (a2 + a3);
    }
    if (s < LEN) {
      const float* hp = hc + (size_t)(B0 + b8) * HID + ks * 128;
      float r0 = 0, r1 = 0, r2 = 0, r3 = 0;
      float z0 = 0, z1 = 0, z2 = 0, z3 = 0;
      float n0 = 0, n1 = 0, n2 = 0, n3 = 0;
#pragma unroll 4
      for (int k = 0; k < 128; k += 4) {
        float4 h4 = *(const float4*)(hp + k);
        float4 w0 = *(const float4*)(wr0 + k);
        float4 w1 = *(const float4*)(wr1 + k);
        float4 w2 = *(const float4*)(wr2 + k);
        r0 += w0.x * h4.x; r1 += w0.y * h4.y; r2 += w0.z * h4.z; r3 += w0.w * h4.w;
        z0 += w1.x * h4.x; z1 += w1.y * h4.y; z2 += w1.z * h4.z; z3 += w1.w * h4.w;
        n0 += w2.x * h4.x; n1 += w2.y * h4.y; n2 += w2.z * h4.z; n3 += w2.w * h4.w;
      }
      ghp[ks][0][d_gh][b8] = (r0 + r1) + (r2 + r3);
      ghp[ks][1][d_gh][b8] = (z0 + z1) + (z2 + z3);
      ghp[ks][2][d_gh][b8] = (n0 + n1) + (n2 + n3);
    }
    __syncthreads();

    // ---- pred reduce over kh ----
    if (s > 0 && tid < 256) {
      int v = tid & 31, bb = tid >> 5;
      predLds[bb][v] = predp[0][bb][v] + predp[1][bb][v] + bov;
    }
    __syncthreads();

    // ---- out row (s-1) + token argmax ----
    if (s > 0 && isOutBlk && tid < 256) {
      int v = tid & 31, bb = tid >> 5;
      out[((size_t)(B0 + bb) * LEN + (s - 1)) * VOC + v] = predLds[bb][v];
    }
    if (s == LEN) break;
    if (tid < 8) {
      if (s == 0) {
        tokLds[tid] = 1;  // SOS
      } else {
        float best = predLds[tid][0]; int bi = 0;
        for (int v = 1; v < VOC; ++v) {
          float x = predLds[tid][v];
          if (x > best) { best = x; bi = v; }
        }
        tokLds[tid] = bi;
      }
    }
    __syncthreads();

    // ---- gates + h_{s+1} write (tid < 128) ----
    if (tid < 128) {
      const int dfull = D0 + g_d;
      const int tk = tokLds[g_b];
      const float* ge = gie + (size_t)tk * 1536;
      const float* gc = gic + (size_t)(B0 + g_b) * 1536;
      float gir = ge[dfull]           + gc[dfull];
      float giz = ge[HID + dfull]     + gc[HID + dfull];
      float gin = ge[2 * HID + dfull] + gc[2 * HID + dfull];
      float ghr = ((ghp[0][0][g_d][g_b] + ghp[1][0][g_d][g_b]) +
                   (ghp[2][0][g_d][g_b] + ghp[3][0][g_d][g_b])) + bh0;
      float ghz = ((ghp[0][1][g_d][g_b] + ghp[1][1][g_d][g_b]) +
                   (ghp[2][1][g_d][g_b] + ghp[3][1][g_d][g_b])) + bh1;
      float ghn = ((ghp[0][2][g_d][g_b] + ghp[1][2][g_d][g_b]) +
                   (ghp[2][2][g_d][g_b] + ghp[3][2][g_d][g_b])) + bh2;
      float r = 1.f / (1.f + expf(-(gir + ghr)));
      float z = 1.f / (1.f + expf(-(giz + ghz)));
      float n = tanhf(gin + r * ghn);
      float hold = hc[(size_t)(B0 + g_b) * HID + dfull];
      float hn = (1.f - z) * n + z * hold;
      hbufs[(size_t)(s + 1) * (HID * BATCH) + (size_t)(B0 + g_b) * HID + dfull] = hn;
    }
    __syncthreads();   // all waves' h stores issued before the release fence

    // ---- flag-vector grid barrier ----
    if (tid == 0) {
      __builtin_amdgcn_fence(__ATOMIC_RELEASE, "agent");   // wbl2: h -> IC
      __hip_atomic_store(&flags[bk * 8], s + 1, __ATOMIC_RELEASE,
                         __HIP_MEMORY_SCOPE_AGENT);
    }
    if (tid < 64) {
      for (;;) {
        int f0 = __hip_atomic_load(&flags[tid * 8], __ATOMIC_RELAXED,
                                   __HIP_MEMORY_SCOPE_AGENT);
        int f1 = __hip_atomic_load(&flags[(64 + tid) * 8], __ATOMIC_RELAXED,
                                   __HIP_MEMORY_SCOPE_AGENT);
        if (__all(f0 > s && f1 > s)) break;
        __builtin_amdgcn_s_sleep(4);   // back off ~256 cyc: keep IC path clear
      }
    }
    __syncthreads();
    __builtin_amdgcn_fence(__ATOMIC_ACQUIRE, "workgroup");  // compiler ordering
  }
}

extern "C" void kernel_launch(void* const* d_in, const int* in_sizes, int n_in,
                              void* d_out, int out_size, void* d_ws, size_t ws_size,
                              hipStream_t stream) {
  (void)in_sizes; (void)n_in; (void)out_size; (void)ws_size;
  const float* enc   = (const float*)d_in[0];
  const float* emb   = (const float*)d_in[1];
  const float* Wattn = (const float*)d_in[2];
  // d_in[3] b_attn: constant shift, cancels in softmax
  const float* Wih  = (const float*)d_in[4];
  const float* Whh  = (const float*)d_in[5];
  const float* bih  = (const float*)d_in[6];
  const float* bhh  = (const float*)d_in[7];
  const float* Wout = (const float*)d_in[8];
  const float* bout = (const float*)d_in[9];

  float* ws    = (float*)d_ws;
  float* gic   = ws;                    // 49152
  float* gie   = ws + 49152;            // 49152
  float* hbufs = ws + 98304;            // 101 * 16384
  float* score    = ws + 131072;        // alias: h bufs 2..5 (precompute only)
  float* ctx_part = ws + 196608;        // alias: h bufs 6..7
  float* ctx      = ws + 229376;        // alias: h buf 8 (half)
  int*   flags = (int*)(ws + 1753088);  // 1024 ints
  float* out   = (float*)d_out;

  k_init<<<64, 256, 0, stream>>>(hbufs, flags);
  k_score<<<16384, 256, 0, stream>>>(enc, Wattn, score);
  k_softmax<<<32, 256, 0, stream>>>(score);
  k_ctxpart<<<128, 256, 0, stream>>>(enc, score, ctx_part);
  k_ctxreduce<<<32, 256, 0, stream>>>(ctx_part, ctx);
  k_gitab<<<192, 256, 0, stream>>>(Wih, bih, emb, ctx, gic, gie);

  k_seq<<<NBLK, NTHR, 0, stream>>>(Whh, bhh, Wout, bout, gic, gie,
                                   hbufs, flags, out);
}

// Round 7
// 3333.651 us; speedup vs baseline: 1.0928x; 1.0928x over previous
//
#include <hip/hip_runtime.h>
#include <math.h>

#define T_ENC 2048
#define BATCH 32
#define DM    256
#define HID   512
#define VOC   32
#define LEN   100
#define NBLK  128
#define NTHR  512

// ws layout (floats):
// [0,      49152)    gi_const [b][1536]
// [49152,  98304)    gi_emb   [v][1536]
// [98304, 1753088)   h bufs: 101 x [b][k] (32x512), fresh buffer per step
//    precompute-only aliases (dead before k_seq; k_seq entry does an
//    agent-acquire (buffer_inv) per block so no stale L1/L2 copies):
//    score    at 131072 (= h bufs 2..5), ctx_part at 196608 (= bufs 6..7),
//    ctx      at 229376 (= buf 8 half)
// [1753088,1754112)  flags: 4 groups x 32 ints padded x8 (32B apart)

// ---------- precompute ----------

__global__ void k_score(const float* __restrict__ enc, const float* __restrict__ Wattn,
                        float* __restrict__ score) {
  int wid  = (blockIdx.x * blockDim.x + threadIdx.x) >> 6;
  int lane = threadIdx.x & 63;
  int b = wid & 31, t = wid >> 5;
  const float4 e4 = *(const float4*)(enc + (size_t)(t * BATCH + b) * DM + lane * 4);
  const float4 w4 = *(const float4*)(Wattn + HID + lane * 4);
  float v = e4.x * w4.x + e4.y * w4.y + e4.z * w4.z + e4.w * w4.w;
  for (int o = 32; o; o >>= 1) v += __shfl_down(v, o);
  if (lane == 0) score[b * T_ENC + t] = v;
}

__global__ void k_softmax(float* __restrict__ score) {
  int b = blockIdx.x, tid = threadIdx.x;
  float* row = score + b * T_ENC;
  float4 v0 = *(const float4*)(row + tid * 8);
  float4 v1 = *(const float4*)(row + tid * 8 + 4);
  float m = fmaxf(fmaxf(fmaxf(v0.x, v0.y), fmaxf(v0.z, v0.w)),
                  fmaxf(fmaxf(v1.x, v1.y), fmaxf(v1.z, v1.w)));
  for (int o = 32; o; o >>= 1) m = fmaxf(m, __shfl_xor(m, o));
  __shared__ float redm[8];
  __shared__ float reds[8];
  if ((tid & 63) == 0) redm[tid >> 6] = m;
  __syncthreads();
  m = fmaxf(fmaxf(redm[0], redm[1]), fmaxf(redm[2], redm[3]));
  float e0 = expf(v0.x - m), e1 = expf(v0.y - m), e2 = expf(v0.z - m), e3 = expf(v0.w - m);
  float e4 = expf(v1.x - m), e5 = expf(v1.y - m), e6 = expf(v1.z - m), e7 = expf(v1.w - m);
  float s = ((e0 + e1) + (e2 + e3)) + ((e4 + e5) + (e6 + e7));
  for (int o = 32; o; o >>= 1) s += __shfl_xor(s, o);
  if ((tid & 63) == 0) reds[tid >> 6] = s;
  __syncthreads();
  s = (reds[0] + reds[1]) + (reds[2] + reds[3]);
  float inv = 1.f / s;
  float4 o0 = {e0 * inv, e1 * inv, e2 * inv, e3 * inv};
  float4 o1 = {e4 * inv, e5 * inv, e6 * inv, e7 * inv};
  *(float4*)(row + tid * 8)     = o0;
  *(float4*)(row + tid * 8 + 4) = o1;
}

__global__ void k_ctxpart(const float* __restrict__ enc, const float* __restrict__ aw,
                          float* __restrict__ ctx_part) {
  int b = blockIdx.x >> 2, tg = blockIdx.x & 3;
  int w = threadIdx.x >> 6, lane = threadIdx.x & 63;
  float4 acc = {0.f, 0.f, 0.f, 0.f};
  for (int i = 0; i < 128; ++i) {
    int t = tg * 512 + w * 128 + i;
    float a = aw[b * T_ENC + t];
    const float4 e4 = *(const float4*)(enc + (size_t)(t * BATCH + b) * DM + lane * 4);
    acc.x += a * e4.x; acc.y += a * e4.y; acc.z += a * e4.z; acc.w += a * e4.w;
  }
  __shared__ float4 part[4][64];
  part[w][lane] = acc;
  __syncthreads();
  if (w == 0) {
    float4 s = part[0][lane], p1 = part[1][lane], p2 = part[2][lane], p3 = part[3][lane];
    s.x += p1.x + p2.x + p3.x; s.y += p1.y + p2.y + p3.y;
    s.z += p1.z + p2.z + p3.z; s.w += p1.w + p2.w + p3.w;
    *(float4*)(ctx_part + (size_t)(tg * BATCH + b) * DM + lane * 4) = s;
  }
}

__global__ void k_ctxreduce(const float* __restrict__ ctx_part, float* __restrict__ ctx) {
  int b = blockIdx.x, d = threadIdx.x;
  float s = 0.f;
  for (int tg = 0; tg < 4; ++tg) s += ctx_part[(size_t)(tg * BATCH + b) * DM + d];
  ctx[b * DM + d] = s;
}

__global__ void k_gitab(const float* __restrict__ Wih, const float* __restrict__ bih,
                        const float* __restrict__ emb, const float* __restrict__ ctx,
                        float* __restrict__ gi_const, float* __restrict__ gi_emb) {
  int idx = threadIdx.x & 31, rs = threadIdx.x >> 5;
  int row = blockIdx.x * 8 + rs;
  const float* wr = Wih + (size_t)row * (2 * DM);
  const float* c = ctx + idx * DM;
  const float* e = emb + idx * DM;
  float accC = 0.f, accE = 0.f;
  for (int k = 0; k < DM; k += 4) {
    float4 we = *(const float4*)(wr + k);
    float4 wc = *(const float4*)(wr + DM + k);
    float4 cv = *(const float4*)(c + k);
    float4 ev = *(const float4*)(e + k);
    accE += we.x * ev.x + we.y * ev.y + we.z * ev.z + we.w * ev.w;
    accC += wc.x * cv.x + wc.y * cv.y + wc.z * cv.z + wc.w * cv.w;
  }
  gi_const[idx * 1536 + row] = accC + bih[row];
  gi_emb[idx * 1536 + row]   = accE;
}

__global__ void k_init(float* __restrict__ h0, int* __restrict__ flags) {
  int i = blockIdx.x * blockDim.x + threadIdx.x;
  if (i < HID * BATCH) h0[i] = 0.f;
  if (i < 1024) flags[i] = 0;
}

// ---------- persistent recurrence ----------
// 4 INDEPENDENT groups of 32 blocks. Group g owns batches [g*8, g*8+8);
// block m in group owns h-dims [m*16, m*16+16). Cross-block data = h only,
// published via sc1 write-through atomic stores (NO agent fences -> no wbl2),
// synced by group-local flag vector (parallel stores, wave-wide poll).
__global__ __launch_bounds__(NTHR) void k_seq(
    const float* __restrict__ Whh, const float* __restrict__ bhh,
    const float* __restrict__ Wout, const float* __restrict__ bout,
    const float* __restrict__ gic, const float* __restrict__ gie,
    float* __restrict__ hbufs, int* __restrict__ flags,
    float* __restrict__ out) {
  // one-time invalidate of any stale L1/L2 lines (aliased precompute scratch)
  __builtin_amdgcn_fence(__ATOMIC_ACQUIRE, "agent");

  const int tid = threadIdx.x, bk = blockIdx.x;
  const int g  = bk >> 5, m = bk & 31;
  const int B0 = g * 8;              // batch-group base (8 batches)
  const int D0 = m * 16;             // dim-group base (16 dims)
  int* fgrp = flags + g * 32 * 8;    // group-local flag vector

  __shared__ float ghp[4][3][16][9];   // [ks][gate][d][b8] pad 9
  __shared__ float predp[2][8][36];    // [kh][b8][v] pad 36
  __shared__ int   tokLds[8];

  // phase-1 thread maps
  const int b8 = tid & 7;
  const int q  = tid >> 3;                 // 0..63
  const int d_gh = q & 15, ks = q >> 4;    // gh: dim, k-quarter
  const int v_pr = q & 31, kh = q >> 5;    // pred: vocab, k-half

  const float* wr0 = Whh + (size_t)(          D0 + d_gh) * HID + ks * 128;
  const float* wr1 = Whh + (size_t)(HID     + D0 + d_gh) * HID + ks * 128;
  const float* wr2 = Whh + (size_t)(2 * HID + D0 + d_gh) * HID + ks * 128;
  const float* wo  = Wout + (size_t)v_pr * HID + kh * 256;
  const float  bov = bout[tid & 31];

  // gates-phase constants (tid < 128): d = tid&15, b = tid>>4
  const int g_d = tid & 15, g_b = tid >> 4;
  float bh0 = 0.f, bh1 = 0.f, bh2 = 0.f;
  if (tid < 128) {
    bh0 = bhh[D0 + g_d]; bh1 = bhh[HID + D0 + g_d]; bh2 = bhh[2 * HID + D0 + g_d];
  }

  for (int s = 0; s <= LEN; ++s) {
    const float* hc = hbufs + (size_t)s * (HID * BATCH);

    // ---- partials: pred (step s-1) and gh (step s), both from h_s ----
    if (s > 0) {
      const float* hp = hc + (size_t)(B0 + b8) * HID + kh * 256;
      float a0 = 0.f, a1 = 0.f, a2 = 0.f, a3 = 0.f;
#pragma unroll 8
      for (int k = 0; k < 256; k += 4) {
        float4 h4 = *(const float4*)(hp + k);
        float4 w4 = *(const float4*)(wo + k);
        a0 += h4.x * w4.x; a1 += h4.y * w4.y; a2 += h4.z * w4.z; a3 += h4.w * w4.w;
      }
      predp[kh][b8][v_pr] = (a0 + a1) + (a2 + a3);
    }
    if (s < LEN) {
      const float* hp = hc + (size_t)(B0 + b8) * HID + ks * 128;
      float r0 = 0, r1 = 0, r2 = 0, r3 = 0;
      float z0 = 0, z1 = 0, z2 = 0, z3 = 0;
      float n0 = 0, n1 = 0, n2 = 0, n3 = 0;
#pragma unroll 4
      for (int k = 0; k < 128; k += 4) {
        float4 h4 = *(const float4*)(hp + k);
        float4 w0 = *(const float4*)(wr0 + k);
        float4 w1 = *(const float4*)(wr1 + k);
        float4 w2 = *(const float4*)(wr2 + k);
        r0 += w0.x * h4.x; r1 += w0.y * h4.y; r2 += w0.z * h4.z; r3 += w0.w * h4.w;
        z0 += w1.x * h4.x; z1 += w1.y * h4.y; z2 += w1.z * h4.z; z3 += w1.w * h4.w;
        n0 += w2.x * h4.x; n1 += w2.y * h4.y; n2 += w2.z * h4.z; n3 += w2.w * h4.w;
      }
      ghp[ks][0][d_gh][b8] = (r0 + r1) + (r2 + r3);
      ghp[ks][1][d_gh][b8] = (z0 + z1) + (z2 + z3);
      ghp[ks][2][d_gh][b8] = (n0 + n1) + (n2 + n3);
    }
    __syncthreads();

    // ---- pred reduce + out write + argmax via 32-lane shuffle (tid<256) ----
    if (s == 0) {
      if (tid < 8) tokLds[tid] = 1;  // SOS
    } else if (tid < 256) {
      const int v = tid & 31, bb = tid >> 5;
      float val = predp[0][bb][v] + predp[1][bb][v] + bov;
      if (m == 0)
        out[((size_t)(B0 + bb) * LEN + (s - 1)) * VOC + v] = val;
      if (s < LEN) {
        unsigned xi = __float_as_uint(val);
        xi = (xi & 0x80000000u) ? ~xi : (xi | 0x80000000u);
        unsigned long long key =
            ((unsigned long long)xi << 6) | (unsigned long long)(63 - v);
#pragma unroll
        for (int o = 16; o; o >>= 1) {
          unsigned long long ok = __shfl_xor(key, o, 32);
          key = ok > key ? ok : key;
        }
        if (v == 0) tokLds[bb] = 63 - (int)(key & 63ull);
      }
    }
    if (s == LEN) break;
    __syncthreads();

    // ---- gates + h_{s+1} publish (tid < 128), sc1 write-through ----
    if (tid < 128) {
      const int dfull = D0 + g_d;
      const int tk = tokLds[g_b];
      const float* ge = gie + (size_t)tk * 1536;
      const float* gc = gic + (size_t)(B0 + g_b) * 1536;
      float gir = ge[dfull]           + gc[dfull];
      float giz = ge[HID + dfull]     + gc[HID + dfull];
      float gin = ge[2 * HID + dfull] + gc[2 * HID + dfull];
      float ghr = ((ghp[0][0][g_d][g_b] + ghp[1][0][g_d][g_b]) +
                   (ghp[2][0][g_d][g_b] + ghp[3][0][g_d][g_b])) + bh0;
      float ghz = ((ghp[0][1][g_d][g_b] + ghp[1][1][g_d][g_b]) +
                   (ghp[2][1][g_d][g_b] + ghp[3][1][g_d][g_b])) + bh1;
      float ghn = ((ghp[0][2][g_d][g_b] + ghp[1][2][g_d][g_b]) +
                   (ghp[2][2][g_d][g_b] + ghp[3][2][g_d][g_b])) + bh2;
      float r = 1.f / (1.f + expf(-(gir + ghr)));
      float z = 1.f / (1.f + expf(-(giz + ghz)));
      float n = tanhf(gin + r * ghn);
      float hold = hc[(size_t)(B0 + g_b) * HID + dfull];
      float hn = (1.f - z) * n + z * hold;
      __hip_atomic_store(
          &hbufs[(size_t)(s + 1) * (HID * BATCH) + (size_t)(B0 + g_b) * HID + dfull],
          hn, __ATOMIC_RELAXED, __HIP_MEMORY_SCOPE_AGENT);
    }
    // every wave drains its stores (acked at IC) before crossing the barrier
    asm volatile("s_waitcnt vmcnt(0)" ::: "memory");
    __syncthreads();

    // ---- group-local flag-vector barrier (no fences, no RMW) ----
    if (tid == 0)
      __hip_atomic_store(fgrp + m * 8, s + 1, __ATOMIC_RELAXED,
                         __HIP_MEMORY_SCOPE_AGENT);
    if (tid < 64) {
      const int idx = (tid & 31) * 8;
      for (;;) {
        int f = __hip_atomic_load(fgrp + idx, __ATOMIC_RELAXED,
                                  __HIP_MEMORY_SCOPE_AGENT);
        if (__all(f > s)) break;
        __builtin_amdgcn_s_sleep(1);
      }
    }
    __syncthreads();
  }
}

extern "C" void kernel_launch(void* const* d_in, const int* in_sizes, int n_in,
                              void* d_out, int out_size, void* d_ws, size_t ws_size,
                              hipStream_t stream) {
  (void)in_sizes; (void)n_in; (void)out_size; (void)ws_size;
  const float* enc   = (const float*)d_in[0];
  const float* emb   = (const float*)d_in[1];
  const float* Wattn = (const float*)d_in[2];
  // d_in[3] b_attn: constant shift, cancels in softmax
  const float* Wih  = (const float*)d_in[4];
  const float* Whh  = (const float*)d_in[5];
  const float* bih  = (const float*)d_in[6];
  const float* bhh  = (const float*)d_in[7];
  const float* Wout = (const float*)d_in[8];
  const float* bout = (const float*)d_in[9];

  float* ws    = (float*)d_ws;
  float* gic   = ws;                    // 49152
  float* gie   = ws + 49152;            // 49152
  float* hbufs = ws + 98304;            // 101 * 16384
  float* score    = ws + 131072;        // alias: h bufs 2..5 (precompute only)
  float* ctx_part = ws + 196608;        // alias: h bufs 6..7
  float* ctx      = ws + 229376;        // alias: h buf 8 (half)
  int*   flags = (int*)(ws + 1753088);  // 1024 ints
  float* out   = (float*)d_out;

  k_init<<<64, 256, 0, stream>>>(hbufs, flags);
  k_score<<<16384, 256, 0, stream>>>(enc, Wattn, score);
  k_softmax<<<32, 256, 0, stream>>>(score);
  k_ctxpart<<<128, 256, 0, stream>>>(enc, score, ctx_part);
  k_ctxreduce<<<32, 256, 0, stream>>>(ctx_part, ctx);
  k_gitab<<<192, 256, 0, stream>>>(Wih, bih, emb, ctx, gic, gie);

  k_seq<<<NBLK, NTHR, 0, stream>>>(Whh, bhh, Wout, bout, gic, gie,
                                   hbufs, flags, out);
}

// Round 8
// 803.666 us; speedup vs baseline: 4.5331x; 4.1481x over previous
//
#include <hip/hip_runtime.h>
#include <math.h>

#define T_ENC 2048
#define BATCH 32
#define DM    256
#define HID   512
#define VOC   32
#define LEN   100
#define NBLK  256
#define NTHR  512
#define BPG   4     // batches per group (8 groups x 32 blocks)

// ws layout (floats):
// [0,      49152)    gi_const [b][1536]
// [49152,  98304)    gi_emb   [v][1536]
// [98304, 1753088)   h bufs: 101 x [b][k] (32x512), fresh buffer per step
//    precompute-only aliases (dead before k_seq; end-of-dispatch L2 flush +
//    k_seq entry agent-acquire make them safe):
//    score at 131072, ctx_part at 196608, ctx at 229376
// [1753088,1959936)  flags: [101][256][8] ints, FRESH slot per step
//    (never zeroed: poll compares == s+1, poison 0xAAAAAAAA never matches)

// ---------- precompute ----------

__global__ void k_score(const float* __restrict__ enc, const float* __restrict__ Wattn,
                        float* __restrict__ score) {
  int wid  = (blockIdx.x * blockDim.x + threadIdx.x) >> 6;
  int lane = threadIdx.x & 63;
  int b = wid & 31, t = wid >> 5;
  const float4 e4 = *(const float4*)(enc + (size_t)(t * BATCH + b) * DM + lane * 4);
  const float4 w4 = *(const float4*)(Wattn + HID + lane * 4);
  float v = e4.x * w4.x + e4.y * w4.y + e4.z * w4.z + e4.w * w4.w;
  for (int o = 32; o; o >>= 1) v += __shfl_down(v, o);
  if (lane == 0) score[b * T_ENC + t] = v;
}

__global__ void k_softmax(float* __restrict__ score) {
  int b = blockIdx.x, tid = threadIdx.x;
  float* row = score + b * T_ENC;
  float4 v0 = *(const float4*)(row + tid * 8);
  float4 v1 = *(const float4*)(row + tid * 8 + 4);
  float m = fmaxf(fmaxf(fmaxf(v0.x, v0.y), fmaxf(v0.z, v0.w)),
                  fmaxf(fmaxf(v1.x, v1.y), fmaxf(v1.z, v1.w)));
  for (int o = 32; o; o >>= 1) m = fmaxf(m, __shfl_xor(m, o));
  __shared__ float redm[8];
  __shared__ float reds[8];
  if ((tid & 63) == 0) redm[tid >> 6] = m;
  __syncthreads();
  m = fmaxf(fmaxf(redm[0], redm[1]), fmaxf(redm[2], redm[3]));
  float e0 = expf(v0.x - m), e1 = expf(v0.y - m), e2 = expf(v0.z - m), e3 = expf(v0.w - m);
  float e4 = expf(v1.x - m), e5 = expf(v1.y - m), e6 = expf(v1.z - m), e7 = expf(v1.w - m);
  float s = ((e0 + e1) + (e2 + e3)) + ((e4 + e5) + (e6 + e7));
  for (int o = 32; o; o >>= 1) s += __shfl_xor(s, o);
  if ((tid & 63) == 0) reds[tid >> 6] = s;
  __syncthreads();
  s = (reds[0] + reds[1]) + (reds[2] + reds[3]);
  float inv = 1.f / s;
  float4 o0 = {e0 * inv, e1 * inv, e2 * inv, e3 * inv};
  float4 o1 = {e4 * inv, e5 * inv, e6 * inv, e7 * inv};
  *(float4*)(row + tid * 8)     = o0;
  *(float4*)(row + tid * 8 + 4) = o1;
}

__global__ void k_ctxpart(const float* __restrict__ enc, const float* __restrict__ aw,
                          float* __restrict__ ctx_part) {
  int b = blockIdx.x >> 2, tg = blockIdx.x & 3;
  int w = threadIdx.x >> 6, lane = threadIdx.x & 63;
  float4 acc = {0.f, 0.f, 0.f, 0.f};
  for (int i = 0; i < 128; ++i) {
    int t = tg * 512 + w * 128 + i;
    float a = aw[b * T_ENC + t];
    const float4 e4 = *(const float4*)(enc + (size_t)(t * BATCH + b) * DM + lane * 4);
    acc.x += a * e4.x; acc.y += a * e4.y; acc.z += a * e4.z; acc.w += a * e4.w;
  }
  __shared__ float4 part[4][64];
  part[w][lane] = acc;
  __syncthreads();
  if (w == 0) {
    float4 s = part[0][lane], p1 = part[1][lane], p2 = part[2][lane], p3 = part[3][lane];
    s.x += p1.x + p2.x + p3.x; s.y += p1.y + p2.y + p3.y;
    s.z += p1.z + p2.z + p3.z; s.w += p1.w + p2.w + p3.w;
    *(float4*)(ctx_part + (size_t)(tg * BATCH + b) * DM + lane * 4) = s;
  }
}

__global__ void k_ctxreduce(const float* __restrict__ ctx_part, float* __restrict__ ctx) {
  int b = blockIdx.x, d = threadIdx.x;
  float s = 0.f;
  for (int tg = 0; tg < 4; ++tg) s += ctx_part[(size_t)(tg * BATCH + b) * DM + d];
  ctx[b * DM + d] = s;
}

__global__ void k_gitab(const float* __restrict__ Wih, const float* __restrict__ bih,
                        const float* __restrict__ emb, const float* __restrict__ ctx,
                        float* __restrict__ gi_const, float* __restrict__ gi_emb) {
  int idx = threadIdx.x & 31, rs = threadIdx.x >> 5;
  int row = blockIdx.x * 8 + rs;
  const float* wr = Wih + (size_t)row * (2 * DM);
  const float* c = ctx + idx * DM;
  const float* e = emb + idx * DM;
  float accC = 0.f, accE = 0.f;
  for (int k = 0; k < DM; k += 4) {
    float4 we = *(const float4*)(wr + k);
    float4 wc = *(const float4*)(wr + DM + k);
    float4 cv = *(const float4*)(c + k);
    float4 ev = *(const float4*)(e + k);
    accE += we.x * ev.x + we.y * ev.y + we.z * ev.z + we.w * ev.w;
    accC += wc.x * cv.x + wc.y * cv.y + wc.z * cv.z + wc.w * cv.w;
  }
  gi_const[idx * 1536 + row] = accC + bih[row];
  gi_emb[idx * 1536 + row]   = accE;
}

__global__ void k_init(float* __restrict__ h0) {
  int i = blockIdx.x * blockDim.x + threadIdx.x;
  if (i < HID * BATCH) h0[i] = 0.f;
}

// ---------- persistent recurrence ----------
// 256 blocks x 512 thr = 8 groups(4 batches) x 32 dim-blocks(16 dims).
// Wout LDS-resident (loaded once); h staged to LDS per step; only per-step
// global stream = 96 KB Whh slice (deep unroll, VGPR headroom for MLP).
// Cross-block data = h only, published sc1 write-through; fresh flag
// address per step (poll == s+1; 0xAA poison never matches).
__global__ __launch_bounds__(NTHR, 2) void k_seq(
    const float* __restrict__ Whh, const float* __restrict__ bhh,
    const float* __restrict__ Wout, const float* __restrict__ bout,
    const float* __restrict__ gic, const float* __restrict__ gie,
    float* __restrict__ hbufs, int* __restrict__ flags,
    float* __restrict__ out) {
  __builtin_amdgcn_fence(__ATOMIC_ACQUIRE, "agent");  // one-time inv

  const int tid = threadIdx.x, bk = blockIdx.x;
  const int g = bk >> 5, m = bk & 31;
  const int B0 = g * BPG;            // 4 batches
  const int D0 = m * 16;             // 16 dims

  __shared__ float woutT[HID][33];      // [k][v], 67.6 KB, bank (k+v)%32
  __shared__ float hbk[BPG][520];       // h [b][k], 8.3 KB
  __shared__ float ghp[8][3][16][4];    // [ks][gate][d][b], 6 KB
  __shared__ float predp[16][BPG][33];  // [kq][b][v], 8.4 KB
  __shared__ int   tokLds[BPG];

  // one-time: Wout -> LDS transposed (coalesced global, conflict-free LDS)
  {
    const int k = tid;
    for (int v = 0; v < VOC; ++v)
      woutT[k][v] = Wout[(size_t)v * HID + k];
  }

  // thread maps
  const int sb = tid >> 7, sk4 = tid & 127;                   // stage
  const int gb = tid & 3, gd = (tid >> 2) & 15, gks = tid >> 6; // gh
  const int pv = tid & 31, pq = tid >> 5;                     // pred
  const float bov = bout[pv];

  const float* wr0 = Whh + (size_t)(          D0 + gd) * HID + gks * 64;
  const float* wr1 = Whh + (size_t)(HID     + D0 + gd) * HID + gks * 64;
  const float* wr2 = Whh + (size_t)(2 * HID + D0 + gd) * HID + gks * 64;

  const int eb = tid >> 4, ed = tid & 15;                     // gates (tid<64)
  float bh0 = 0.f, bh1 = 0.f, bh2 = 0.f;
  if (tid < 64) {
    bh0 = bhh[D0 + ed]; bh1 = bhh[HID + D0 + ed]; bh2 = bhh[2 * HID + D0 + ed];
  }
  __syncthreads();  // woutT ready

  for (int s = 0; s <= LEN; ++s) {
    const float* hc = hbufs + (size_t)s * (HID * BATCH) + (size_t)B0 * HID;

    // ---- stage h_s (4 batches x 512) into LDS ----
    {
      float4 hv = *(const float4*)(hc + (size_t)sb * HID + sk4 * 4);
      *(float4*)(&hbk[sb][sk4 * 4]) = hv;
    }
    __syncthreads();

    // ---- pred partials (step s-1 logits): thread (pv, kq), all from LDS ----
    if (s > 0) {
      const int k0 = pq * 32;
      float a0 = 0.f, a1 = 0.f, a2 = 0.f, a3 = 0.f;
#pragma unroll 8
      for (int j = 0; j < 32; ++j) {
        float w = woutT[k0 + j][pv];
        a0 += w * hbk[0][k0 + j]; a1 += w * hbk[1][k0 + j];
        a2 += w * hbk[2][k0 + j]; a3 += w * hbk[3][k0 + j];
      }
      predp[pq][0][pv] = a0; predp[pq][1][pv] = a1;
      predp[pq][2][pv] = a2; predp[pq][3][pv] = a3;
    }

    // ---- gh partials: thread (gb, gd, gks); W from global (only stream) ----
    if (s < LEN) {
      const float* hp = &hbk[gb][gks * 64];
      float r0 = 0, r1 = 0, r2 = 0, r3 = 0;
      float z0 = 0, z1 = 0, z2 = 0, z3 = 0;
      float n0 = 0, n1 = 0, n2 = 0, n3 = 0;
#pragma unroll 4
      for (int j = 0; j < 64; j += 4) {
        float4 h4 = *(const float4*)(hp + j);       // LDS, broadcast over gd
        float4 w0 = *(const float4*)(wr0 + j);
        float4 w1 = *(const float4*)(wr1 + j);
        float4 w2 = *(const float4*)(wr2 + j);
        r0 += w0.x * h4.x; r1 += w0.y * h4.y; r2 += w0.z * h4.z; r3 += w0.w * h4.w;
        z0 += w1.x * h4.x; z1 += w1.y * h4.y; z2 += w1.z * h4.z; z3 += w1.w * h4.w;
        n0 += w2.x * h4.x; n1 += w2.y * h4.y; n2 += w2.z * h4.z; n3 += w2.w * h4.w;
      }
      ghp[gks][0][gd][gb] = (r0 + r1) + (r2 + r3);
      ghp[gks][1][gd][gb] = (z0 + z1) + (z2 + z3);
      ghp[gks][2][gd][gb] = (n0 + n1) + (n2 + n3);
    }
    __syncthreads();

    // ---- pred reduce + out write + argmax (tid < 128: b=tid>>5, v=tid&31) ----
    if (s == 0) {
      if (tid < BPG) tokLds[tid] = 1;  // SOS
    } else if (tid < 128) {
      const int v = tid & 31, bb = tid >> 5;
      float val = bov;
#pragma unroll
      for (int q2 = 0; q2 < 16; ++q2) val += predp[q2][bb][v];
      if (m == 0)
        out[((size_t)(B0 + bb) * LEN + (s - 1)) * VOC + v] = val;
      if (s < LEN) {
        unsigned xi = __float_as_uint(val);
        xi = (xi & 0x80000000u) ? ~xi : (xi | 0x80000000u);
        unsigned long long key =
            ((unsigned long long)xi << 6) | (unsigned long long)(63 - v);
#pragma unroll
        for (int o = 16; o; o >>= 1) {
          unsigned long long ok = __shfl_xor(key, o, 32);
          key = ok > key ? ok : key;
        }
        if (v == 0) tokLds[bb] = 63 - (int)(key & 63ull);
      }
    }
    if (s == LEN) break;
    __syncthreads();

    // ---- gates + h_{s+1} publish (tid < 64), sc1 write-through ----
    if (tid < 64) {
      const int dfull = D0 + ed;
      const int tk = tokLds[eb];
      const float* ge = gie + (size_t)tk * 1536;
      const float* gc = gic + (size_t)(B0 + eb) * 1536;
      float gir = ge[dfull]           + gc[dfull];
      float giz = ge[HID + dfull]     + gc[HID + dfull];
      float gin = ge[2 * HID + dfull] + gc[2 * HID + dfull];
      float ghr = bh0, ghz = bh1, ghn = bh2;
#pragma unroll
      for (int ks2 = 0; ks2 < 8; ++ks2) {
        ghr += ghp[ks2][0][ed][eb];
        ghz += ghp[ks2][1][ed][eb];
        ghn += ghp[ks2][2][ed][eb];
      }
      float r = 1.f / (1.f + expf(-(gir + ghr)));
      float z = 1.f / (1.f + expf(-(giz + ghz)));
      float n = tanhf(gin + r * ghn);
      float hold = hbk[eb][dfull];
      float hn = (1.f - z) * n + z * hold;
      __hip_atomic_store(
          &hbufs[(size_t)(s + 1) * (HID * BATCH) + (size_t)(B0 + eb) * HID + dfull],
          hn, __ATOMIC_RELAXED, __HIP_MEMORY_SCOPE_AGENT);
    }
    asm volatile("s_waitcnt vmcnt(0)" ::: "memory");
    __syncthreads();

    // ---- flag barrier: FRESH address per step, parallel stores ----
    if (tid == 0)
      __hip_atomic_store(flags + ((size_t)s * NBLK + bk) * 8, s + 1,
                         __ATOMIC_RELAXED, __HIP_MEMORY_SCOPE_AGENT);
    if (tid < 64) {
      const int* fp = flags + ((size_t)s * NBLK + g * 32 + (tid & 31)) * 8;
      for (;;) {
        int f = __hip_atomic_load(fp, __ATOMIC_RELAXED, __HIP_MEMORY_SCOPE_AGENT);
        if (__all(f == s + 1)) break;
        __builtin_amdgcn_s_sleep(2);
      }
    }
    __syncthreads();
  }
}

extern "C" void kernel_launch(void* const* d_in, const int* in_sizes, int n_in,
                              void* d_out, int out_size, void* d_ws, size_t ws_size,
                              hipStream_t stream) {
  (void)in_sizes; (void)n_in; (void)out_size; (void)ws_size;
  const float* enc   = (const float*)d_in[0];
  const float* emb   = (const float*)d_in[1];
  const float* Wattn = (const float*)d_in[2];
  // d_in[3] b_attn: constant shift, cancels in softmax
  const float* Wih  = (const float*)d_in[4];
  const float* Whh  = (const float*)d_in[5];
  const float* bih  = (const float*)d_in[6];
  const float* bhh  = (const float*)d_in[7];
  const float* Wout = (const float*)d_in[8];
  const float* bout = (const float*)d_in[9];

  float* ws    = (float*)d_ws;
  float* gic   = ws;                    // 49152
  float* gie   = ws + 49152;            // 49152
  float* hbufs = ws + 98304;            // 101 * 16384
  float* score    = ws + 131072;        // alias: h bufs 2..5 (precompute only)
  float* ctx_part = ws + 196608;        // alias: h bufs 6..7
  float* ctx      = ws + 229376;        // alias: h buf 8 (half)
  int*   flags = (int*)(ws + 1753088);  // [101][256][8] ints
  float* out   = (float*)d_out;

  k_init<<<64, 256, 0, stream>>>(hbufs);
  k_score<<<16384, 256, 0, stream>>>(enc, Wattn, score);
  k_softmax<<<32, 256, 0, stream>>>(score);
  k_ctxpart<<<128, 256, 0, stream>>>(enc, score, ctx_part);
  k_ctxreduce<<<32, 256, 0, stream>>>(ctx_part, ctx);
  k_gitab<<<192, 256, 0, stream>>>(Wih, bih, emb, ctx, gic, gie);

  k_seq<<<NBLK, NTHR, 0, stream>>>(Whh, bhh, Wout, bout, gic, gie,
                                   hbufs, flags, out);
}

// Round 9
// 632.093 us; speedup vs baseline: 5.7635x; 1.2714x over previous
//
#include <hip/hip_runtime.h>
#include <math.h>

#define T_ENC 2048
#define BATCH 32
#define DM    256
#define HID   512
#define VOC   32
#define LEN   100
#define NBLK  256
#define NTHR  512
#define BPG   4     // batches per group (8 groups x 32 blocks)

typedef unsigned long long u64;
typedef unsigned int u32;

// ws layout (floats):
// [0,      49152)    gi_const [b][1536]
// [49152,  98304)    gi_emb   [v][1536]
// [98304, 131072)    h pairs: 2 slots x [b][k] (32x512) x u64 {tag,val}
//                    (ping-pong; tag distinguishes steps, 0xAA poison never
//                     matches a real tag)
// [131072,196608)    score (precompute only)
// [196608,229376)    ctx_part
// [229376,237568)    ctx
// k_seq touches only gi_*, pairs, out.

// ---------- precompute ----------

__global__ void k_score(const float* __restrict__ enc, const float* __restrict__ Wattn,
                        float* __restrict__ score) {
  int wid  = (blockIdx.x * blockDim.x + threadIdx.x) >> 6;
  int lane = threadIdx.x & 63;
  int b = wid & 31, t = wid >> 5;
  const float4 e4 = *(const float4*)(enc + (size_t)(t * BATCH + b) * DM + lane * 4);
  const float4 w4 = *(const float4*)(Wattn + HID + lane * 4);
  float v = e4.x * w4.x + e4.y * w4.y + e4.z * w4.z + e4.w * w4.w;
  for (int o = 32; o; o >>= 1) v += __shfl_down(v, o);
  if (lane == 0) score[b * T_ENC + t] = v;
}

__global__ void k_softmax(float* __restrict__ score) {
  int b = blockIdx.x, tid = threadIdx.x;
  float* row = score + b * T_ENC;
  float4 v0 = *(const float4*)(row + tid * 8);
  float4 v1 = *(const float4*)(row + tid * 8 + 4);
  float m = fmaxf(fmaxf(fmaxf(v0.x, v0.y), fmaxf(v0.z, v0.w)),
                  fmaxf(fmaxf(v1.x, v1.y), fmaxf(v1.z, v1.w)));
  for (int o = 32; o; o >>= 1) m = fmaxf(m, __shfl_xor(m, o));
  __shared__ float redm[8];
  __shared__ float reds[8];
  if ((tid & 63) == 0) redm[tid >> 6] = m;
  __syncthreads();
  m = fmaxf(fmaxf(redm[0], redm[1]), fmaxf(redm[2], redm[3]));
  float e0 = expf(v0.x - m), e1 = expf(v0.y - m), e2 = expf(v0.z - m), e3 = expf(v0.w - m);
  float e4 = expf(v1.x - m), e5 = expf(v1.y - m), e6 = expf(v1.z - m), e7 = expf(v1.w - m);
  float s = ((e0 + e1) + (e2 + e3)) + ((e4 + e5) + (e6 + e7));
  for (int o = 32; o; o >>= 1) s += __shfl_xor(s, o);
  if ((tid & 63) == 0) reds[tid >> 6] = s;
  __syncthreads();
  s = (reds[0] + reds[1]) + (reds[2] + reds[3]);
  float inv = 1.f / s;
  float4 o0 = {e0 * inv, e1 * inv, e2 * inv, e3 * inv};
  float4 o1 = {e4 * inv, e5 * inv, e6 * inv, e7 * inv};
  *(float4*)(row + tid * 8)     = o0;
  *(float4*)(row + tid * 8 + 4) = o1;
}

__global__ void k_ctxpart(const float* __restrict__ enc, const float* __restrict__ aw,
                          float* __restrict__ ctx_part) {
  int b = blockIdx.x >> 2, tg = blockIdx.x & 3;
  int w = threadIdx.x >> 6, lane = threadIdx.x & 63;
  float4 acc = {0.f, 0.f, 0.f, 0.f};
  for (int i = 0; i < 128; ++i) {
    int t = tg * 512 + w * 128 + i;
    float a = aw[b * T_ENC + t];
    const float4 e4 = *(const float4*)(enc + (size_t)(t * BATCH + b) * DM + lane * 4);
    acc.x += a * e4.x; acc.y += a * e4.y; acc.z += a * e4.z; acc.w += a * e4.w;
  }
  __shared__ float4 part[4][64];
  part[w][lane] = acc;
  __syncthreads();
  if (w == 0) {
    float4 s = part[0][lane], p1 = part[1][lane], p2 = part[2][lane], p3 = part[3][lane];
    s.x += p1.x + p2.x + p3.x; s.y += p1.y + p2.y + p3.y;
    s.z += p1.z + p2.z + p3.z; s.w += p1.w + p2.w + p3.w;
    *(float4*)(ctx_part + (size_t)(tg * BATCH + b) * DM + lane * 4) = s;
  }
}

__global__ void k_ctxreduce(const float* __restrict__ ctx_part, float* __restrict__ ctx) {
  int b = blockIdx.x, d = threadIdx.x;
  float s = 0.f;
  for (int tg = 0; tg < 4; ++tg) s += ctx_part[(size_t)(tg * BATCH + b) * DM + d];
  ctx[b * DM + d] = s;
}

__global__ void k_gitab(const float* __restrict__ Wih, const float* __restrict__ bih,
                        const float* __restrict__ emb, const float* __restrict__ ctx,
                        float* __restrict__ gi_const, float* __restrict__ gi_emb) {
  int idx = threadIdx.x & 31, rs = threadIdx.x >> 5;
  int row = blockIdx.x * 8 + rs;
  const float* wr = Wih + (size_t)row * (2 * DM);
  const float* c = ctx + idx * DM;
  const float* e = emb + idx * DM;
  float accC = 0.f, accE = 0.f;
  for (int k = 0; k < DM; k += 4) {
    float4 we = *(const float4*)(wr + k);
    float4 wc = *(const float4*)(wr + DM + k);
    float4 cv = *(const float4*)(c + k);
    float4 ev = *(const float4*)(e + k);
    accE += we.x * ev.x + we.y * ev.y + we.z * ev.z + we.w * ev.w;
    accC += wc.x * cv.x + wc.y * cv.y + wc.z * cv.z + wc.w * cv.w;
  }
  gi_const[idx * 1536 + row] = accC + bih[row];
  gi_emb[idx * 1536 + row]   = accE;
}

// init: h_0 pairs = {tag=0, val=0.0f} = ulong 0, written through to IC
__global__ void k_init(u64* __restrict__ pairs) {
  int i = blockIdx.x * blockDim.x + threadIdx.x;
  if (i < BATCH * HID)
    __hip_atomic_store(&pairs[i], 0ull, __ATOMIC_RELAXED, __HIP_MEMORY_SCOPE_AGENT);
}

// ---------- persistent recurrence ----------
// 256 blocks x 512 thr = 8 groups(4 batches) x 32 dim-blocks(16 dims).
// Whh slice in REGISTERS (48 f/thread, loaded once). Wout in LDS. h flows
// between blocks as tagged 8B pairs {tag=step, value}: publish = one sc1
// atomic store (data IS the flag); stage = tag-poll atomic loads. Ping-pong
// 2 slots (tag check makes reuse safe; 2-deep pipelining argument).
__global__ __launch_bounds__(NTHR, 1) void k_seq(
    const float* __restrict__ Whh, const float* __restrict__ bhh,
    const float* __restrict__ Wout, const float* __restrict__ bout,
    const float* __restrict__ gic, const float* __restrict__ gie,
    u64* __restrict__ pairs, float* __restrict__ out) {
  __builtin_amdgcn_fence(__ATOMIC_ACQUIRE, "agent");  // one-time inv

  const int tid = threadIdx.x, bk = blockIdx.x;
  const int g = bk >> 5, m = bk & 31;
  const int B0 = g * BPG;            // 4 batches
  const int D0 = m * 16;             // 16 dims

  __shared__ float woutT[HID][33];      // [k][v] transposed, 67.6 KB
  __shared__ float hbk[BPG][520];       // h [b][k]
  __shared__ float ghp[8][3][16][5];    // [wave][gate][d][b], pad 5
  __shared__ float predp[16][BPG][33];  // [kq][b][v]
  __shared__ int   tokLds[BPG];

  // one-time: Wout -> LDS transposed
  for (int v = 0; v < VOC; ++v)
    woutT[tid][v] = Wout[(size_t)v * HID + tid];

  // one-time: Whh slice -> registers. thread = (d, ksq): 3 gates x 16 k
  const int wd = tid & 15, ksq = tid >> 4;
  const int k0 = ksq * 16;
  float4 wr_[4], wz_[4], wn_[4];
  {
    const float* pr = Whh + (size_t)(          D0 + wd) * HID + k0;
    const float* pz = Whh + (size_t)(HID     + D0 + wd) * HID + k0;
    const float* pn = Whh + (size_t)(2 * HID + D0 + wd) * HID + k0;
#pragma unroll
    for (int j = 0; j < 4; ++j) {
      wr_[j] = ((const float4*)pr)[j];
      wz_[j] = ((const float4*)pz)[j];
      wn_[j] = ((const float4*)pn)[j];
    }
  }

  // other thread maps
  const int sb_ = tid >> 7, sk_ = (tid & 127) * 4;   // stage: 4 pairs
  const int pv = tid & 31, pq = tid >> 5;            // pred partial
  const float bov = bout[pv];
  const int eb = tid >> 4, ed = tid & 15;            // gates (tid<64)
  float bh0 = 0.f, bh1 = 0.f, bh2 = 0.f, gc0 = 0.f, gc1 = 0.f, gc2 = 0.f;
  if (tid < 64) {
    bh0 = bhh[D0 + ed]; bh1 = bhh[HID + D0 + ed]; bh2 = bhh[2 * HID + D0 + ed];
    const float* gc = gic + (size_t)(B0 + eb) * 1536;
    gc0 = gc[D0 + ed]; gc1 = gc[HID + D0 + ed]; gc2 = gc[2 * HID + D0 + ed];
  }
  __syncthreads();  // woutT ready

  for (int s = 0; s <= LEN; ++s) {
    // ---- stage h_s: tag-poll 4 pairs, unpack to LDS ----
    {
      const u64* src = pairs + (size_t)(s & 1) * (BATCH * HID)
                       + (size_t)(B0 + sb_) * HID + sk_;
      u64 u0, u1, u2, u3;
      const u32 want = (u32)s;
      for (;;) {
        u0 = __hip_atomic_load(src + 0, __ATOMIC_RELAXED, __HIP_MEMORY_SCOPE_AGENT);
        u1 = __hip_atomic_load(src + 1, __ATOMIC_RELAXED, __HIP_MEMORY_SCOPE_AGENT);
        u2 = __hip_atomic_load(src + 2, __ATOMIC_RELAXED, __HIP_MEMORY_SCOPE_AGENT);
        u3 = __hip_atomic_load(src + 3, __ATOMIC_RELAXED, __HIP_MEMORY_SCOPE_AGENT);
        if ((u32)u0 == want && (u32)u1 == want && (u32)u2 == want && (u32)u3 == want)
          break;
        __builtin_amdgcn_s_sleep(1);
      }
      float4 hv = {__uint_as_float((u32)(u0 >> 32)), __uint_as_float((u32)(u1 >> 32)),
                   __uint_as_float((u32)(u2 >> 32)), __uint_as_float((u32)(u3 >> 32))};
      *(float4*)(&hbk[sb_][sk_]) = hv;
    }
    __syncthreads();

    // ---- pred partials (logits of step s-1), all LDS ----
    if (s > 0) {
      const int kp = pq * 32;
      float a0 = 0.f, a1 = 0.f, a2 = 0.f, a3 = 0.f;
#pragma unroll 8
      for (int j = 0; j < 32; ++j) {
        float w = woutT[kp + j][pv];
        a0 += w * hbk[0][kp + j]; a1 += w * hbk[1][kp + j];
        a2 += w * hbk[2][kp + j]; a3 += w * hbk[3][kp + j];
      }
      predp[pq][0][pv] = a0; predp[pq][1][pv] = a1;
      predp[pq][2][pv] = a2; predp[pq][3][pv] = a3;
    }

    // ---- gh partials from register W + wave reduce over in-wave ks ----
    if (s < LEN) {
      float accr[BPG], accz[BPG], accn[BPG];
#pragma unroll
      for (int b = 0; b < BPG; ++b) {
        const float* hp = &hbk[b][k0];
        float4 h0 = *(const float4*)(hp + 0);
        float4 h1 = *(const float4*)(hp + 4);
        float4 h2 = *(const float4*)(hp + 8);
        float4 h3 = *(const float4*)(hp + 12);
        accr[b] = wr_[0].x*h0.x + wr_[0].y*h0.y + wr_[0].z*h0.z + wr_[0].w*h0.w
                + wr_[1].x*h1.x + wr_[1].y*h1.y + wr_[1].z*h1.z + wr_[1].w*h1.w
                + wr_[2].x*h2.x + wr_[2].y*h2.y + wr_[2].z*h2.z + wr_[2].w*h2.w
                + wr_[3].x*h3.x + wr_[3].y*h3.y + wr_[3].z*h3.z + wr_[3].w*h3.w;
        accz[b] = wz_[0].x*h0.x + wz_[0].y*h0.y + wz_[0].z*h0.z + wz_[0].w*h0.w
                + wz_[1].x*h1.x + wz_[1].y*h1.y + wz_[1].z*h1.z + wz_[1].w*h1.w
                + wz_[2].x*h2.x + wz_[2].y*h2.y + wz_[2].z*h2.z + wz_[2].w*h2.w
                + wz_[3].x*h3.x + wz_[3].y*h3.y + wz_[3].z*h3.z + wz_[3].w*h3.w;
        accn[b] = wn_[0].x*h0.x + wn_[0].y*h0.y + wn_[0].z*h0.z + wn_[0].w*h0.w
                + wn_[1].x*h1.x + wn_[1].y*h1.y + wn_[1].z*h1.z + wn_[1].w*h1.w
                + wn_[2].x*h2.x + wn_[2].y*h2.y + wn_[2].z*h2.z + wn_[2].w*h2.w
                + wn_[3].x*h3.x + wn_[3].y*h3.y + wn_[3].z*h3.z + wn_[3].w*h3.w;
      }
      const int wv = tid >> 6;
#pragma unroll
      for (int b = 0; b < BPG; ++b) {
        float vr = accr[b], vz = accz[b], vn = accn[b];
        vr += __shfl_down(vr, 32); vr += __shfl_down(vr, 16);
        vz += __shfl_down(vz, 32); vz += __shfl_down(vz, 16);
        vn += __shfl_down(vn, 32); vn += __shfl_down(vn, 16);
        if ((tid & 48) == 0) {
          ghp[wv][0][wd][b] = vr; ghp[wv][1][wd][b] = vz; ghp[wv][2][wd][b] = vn;
        }
      }
    }
    __syncthreads();

    // ---- pred reduce + out write + argmax (tid < 128) ----
    if (s == 0) {
      if (tid < BPG) tokLds[tid] = 1;  // SOS
    } else if (tid < 128) {
      const int v = tid & 31, bb = tid >> 5;
      float val = bov;
#pragma unroll
      for (int q2 = 0; q2 < 16; ++q2) val += predp[q2][bb][v];
      if (m == 0)
        out[((size_t)(B0 + bb) * LEN + (s - 1)) * VOC + v] = val;
      if (s < LEN) {
        unsigned xi = __float_as_uint(val);
        xi = (xi & 0x80000000u) ? ~xi : (xi | 0x80000000u);
        u64 key = ((u64)xi << 6) | (u64)(63 - v);
#pragma unroll
        for (int o = 16; o; o >>= 1) {
          u64 ok = __shfl_xor(key, o, 32);
          key = ok > key ? ok : key;
        }
        if (v == 0) tokLds[bb] = 63 - (int)(key & 63ull);
      }
    }
    if (s == LEN) break;
    __syncthreads();

    // ---- gates + tagged publish of h_{s+1} (tid < 64) ----
    if (tid < 64) {
      const int dfull = D0 + ed;
      const int tk = tokLds[eb];
      const float* ge = gie + (size_t)tk * 1536;
      float gir = ge[dfull]           + gc0;
      float giz = ge[HID + dfull]     + gc1;
      float gin = ge[2 * HID + dfull] + gc2;
      float ghr = bh0, ghz = bh1, ghn = bh2;
#pragma unroll
      for (int w2 = 0; w2 < 8; ++w2) {
        ghr += ghp[w2][0][ed][eb];
        ghz += ghp[w2][1][ed][eb];
        ghn += ghp[w2][2][ed][eb];
      }
      float r = 1.f / (1.f + expf(-(gir + ghr)));
      float z = 1.f / (1.f + expf(-(giz + ghz)));
      float n = tanhf(gin + r * ghn);
      float hold = hbk[eb][dfull];
      float hn = (1.f - z) * n + z * hold;
      u64 pub = ((u64)__float_as_uint(hn) << 32) | (u32)(s + 1);
      __hip_atomic_store(
          pairs + (size_t)((s + 1) & 1) * (BATCH * HID)
                + (size_t)(B0 + eb) * HID + dfull,
          pub, __ATOMIC_RELAXED, __HIP_MEMORY_SCOPE_AGENT);
    }
    __syncthreads();   // hbk/ghp/predp stable until here; next stage overwrites
  }
}

extern "C" void kernel_launch(void* const* d_in, const int* in_sizes, int n_in,
                              void* d_out, int out_size, void* d_ws, size_t ws_size,
                              hipStream_t stream) {
  (void)in_sizes; (void)n_in; (void)out_size; (void)ws_size;
  const float* enc   = (const float*)d_in[0];
  const float* emb   = (const float*)d_in[1];
  const float* Wattn = (const float*)d_in[2];
  // d_in[3] b_attn: constant shift, cancels in softmax
  const float* Wih  = (const float*)d_in[4];
  const float* Whh  = (const float*)d_in[5];
  const float* bih  = (const float*)d_in[6];
  const float* bhh  = (const float*)d_in[7];
  const float* Wout = (const float*)d_in[8];
  const float* bout = (const float*)d_in[9];

  float* ws    = (float*)d_ws;
  float* gic   = ws;                    // 49152
  float* gie   = ws + 49152;            // 49152
  u64*   pairs = (u64*)(ws + 98304);    // 2 x 16384 u64 (32768 floats)
  float* score    = ws + 131072;        // 65536
  float* ctx_part = ws + 196608;        // 32768
  float* ctx      = ws + 229376;        // 8192
  float* out   = (float*)d_out;

  k_init<<<64, 256, 0, stream>>>(pairs);
  k_score<<<16384, 256, 0, stream>>>(enc, Wattn, score);
  k_softmax<<<32, 256, 0, stream>>>(score);
  k_ctxpart<<<128, 256, 0, stream>>>(enc, score, ctx_part);
  k_ctxreduce<<<32, 256, 0, stream>>>(ctx_part, ctx);
  k_gitab<<<192, 256, 0, stream>>>(Wih, bih, emb, ctx, gic, gie);

  k_seq<<<NBLK, NTHR, 0, stream>>>(Whh, bhh, Wout, bout, gic, gie, pairs, out);
}